// Round 7
// baseline (683.640 us; speedup 1.0000x reference)
//
#include <hip/hip_runtime.h>
#include <hip/hip_bf16.h>

typedef __bf16 v8bf __attribute__((ext_vector_type(8)));
typedef float  f32x4 __attribute__((ext_vector_type(4)));

#define KVOL 27
#define KG   4   // taps staged to LDS per group in conv_apply
#define MCB  48  // multi_conv blocks per tap

__device__ __forceinline__ unsigned short f2bf(float f) {
    unsigned int u = __float_as_uint(f);
    u = u + 0x7FFFu + ((u >> 16) & 1u);   // round-to-nearest-even
    return (unsigned short)(u >> 16);
}
__device__ __forceinline__ float bf2f(unsigned short u) {
    return __uint_as_float((unsigned int)u << 16);
}

// ---------------------------------------------------------------------------
// Prep: W [27][64in][64out] fp32 -> bf16 fragments (serves as either MFMA
// operand). lane l, elem i holds W[k][s*32+(l>>4)*8+i][t*16+(l&15)] at ushort
// index (((k*4+t)*2+s)*64 + l)*8 + i.
// ---------------------------------------------------------------------------
__global__ __launch_bounds__(256) void prep_kernel(const float* __restrict__ W,
                                                   unsigned short* __restrict__ wfrag) {
    int d = blockIdx.x * 256 + threadIdx.x;
    if (d < KVOL * 64 * 64) {
        int i    = d & 7;
        int lane = (d >> 3) & 63;
        int s    = (d >> 9) & 1;
        int t    = (d >> 10) & 3;
        int k    = d >> 12;
        int kin  = s * 32 + (lane >> 4) * 8 + i;
        int c    = t * 16 + (lane & 15);
        wfrag[d] = f2bf(W[k * 4096 + kin * 64 + c]);
    }
}

__global__ __launch_bounds__(256) void count_kernel(const int* __restrict__ oidx,
                                                    int* __restrict__ cnt, int M) {
    for (int e = blockIdx.x * 256 + threadIdx.x; e < M; e += gridDim.x * 256)
        atomicAdd(&cnt[oidx[e]], 1);
}

// Compact multi pairs into per-tap slabs: slab[k*Npts + pos] = point id.
__global__ __launch_bounds__(256) void compact_kernel(const int* __restrict__ oidx,
                                                      const int* __restrict__ cnt,
                                                      int* __restrict__ klen,
                                                      int* __restrict__ slab,
                                                      int Npts) {
    const int M = Npts * KVOL;
    for (int e = blockIdx.x * 256 + threadIdx.x; e < M; e += gridDim.x * 256) {
        int o = oidx[e];
        if (cnt[o] > 1) {
            int p = e / KVOL;
            int k = e - p * KVOL;
            int pos = atomicAdd(&klen[k], 1);
            slab[k * Npts + pos] = p;
        }
    }
}

// Zero only multi-contributor rows (cnt >= 2). 4 threads per row.
__global__ __launch_bounds__(256) void zero_multi(float* __restrict__ out,
                                                  const int* __restrict__ cnt, int Nout) {
    const int sub = threadIdx.x & 3;
    const long step = (long)gridDim.x * 64;
    for (long r = (long)blockIdx.x * 64 + (threadIdx.x >> 2); r < Nout; r += step) {
        if (cnt[r] > 1) {
            f32x4 z = {0.f, 0.f, 0.f, 0.f};
            f32x4* p = reinterpret_cast<f32x4*>(out + r * 64) + sub;
            p[0] = z; p[4] = z; p[8] = z; p[12] = z;
        }
    }
}

// ---------------------------------------------------------------------------
// feat_stats: colsum[64] (bf16 precision, fp32 accum) and S = feats^T feats
// (bf16 MFMA, fp32 accum). 128-point tiles; wave w handles points w*32..+32
// as one K=32 MFMA chunk; 16 channel-tile MFMAs per chunk.
// ---------------------------------------------------------------------------
__global__ __launch_bounds__(256) void feat_stats(const float* __restrict__ feats,
                                                  float* __restrict__ colsum,
                                                  float* __restrict__ S,
                                                  int Npts) {
    __shared__ unsigned short As[128 * 64];
    const int tid = threadIdx.x;
    const int w = tid >> 6, l = tid & 63, cl = l & 15, hi = l >> 4;
    const int c = tid & 63, rg = tid >> 6;
    const __bf16* Ab = reinterpret_cast<const __bf16*>(As);

    f32x4 acc[4][4];
    #pragma unroll
    for (int a = 0; a < 4; ++a)
        #pragma unroll
        for (int b = 0; b < 4; ++b) acc[a][b] = (f32x4){0.f, 0.f, 0.f, 0.f};
    float csum = 0.f;

    for (int base = blockIdx.x * 128; base < Npts; base += gridDim.x * 128) {
        __syncthreads();
        #pragma unroll
        for (int e = 0; e < 8; ++e) {
            int lin4 = e * 256 + tid;          // 2048 float4 slots
            int row = lin4 >> 4, col = (lin4 & 15) * 4;
            float4 v = make_float4(0.f, 0.f, 0.f, 0.f);
            if (base + row < Npts)
                v = *reinterpret_cast<const float4*>(feats + (size_t)(base + row) * 64 + col);
            int o = row * 64 + col;
            As[o + 0] = f2bf(v.x); As[o + 1] = f2bf(v.y);
            As[o + 2] = f2bf(v.z); As[o + 3] = f2bf(v.w);
        }
        __syncthreads();
        // colsum partial: thread (c, rg) sums rows rg*32..rg*32+32
        for (int r = 0; r < 32; ++r) csum += bf2f(As[(rg * 32 + r) * 64 + c]);
        // S partial: build 4 column fragments (points w*32+hi*8+i, ch cl+16t)
        v8bf f[4];
        #pragma unroll
        for (int t = 0; t < 4; ++t)
            #pragma unroll
            for (int i = 0; i < 8; ++i)
                f[t][i] = Ab[(w * 32 + hi * 8 + i) * 64 + cl + 16 * t];
        #pragma unroll
        for (int a = 0; a < 4; ++a)
            #pragma unroll
            for (int b = 0; b < 4; ++b)
                acc[a][b] = __builtin_amdgcn_mfma_f32_16x16x32_bf16(f[a], f[b], acc[a][b], 0, 0, 0);
    }

    unsafeAtomicAdd(&colsum[c], csum);
    #pragma unroll
    for (int a = 0; a < 4; ++a)
        #pragma unroll
        for (int b = 0; b < 4; ++b)
            #pragma unroll
            for (int r = 0; r < 4; ++r) {
                int i = a * 16 + hi * 4 + r;   // D row
                int j = b * 16 + cl;           // D col
                unsafeAtomicAdd(&S[i * 64 + j], acc[a][b][r]);
            }
}

// ---------------------------------------------------------------------------
// qall_mean: per tap k (block), per channel c (thread):
//   q_all += w_kc^T S w_kc ;  sum += colsum . w_kc
// ---------------------------------------------------------------------------
__global__ __launch_bounds__(64) void qall_mean(const float* __restrict__ W,
                                                const float* __restrict__ colsum,
                                                const float* __restrict__ S,
                                                float* __restrict__ stats) {
    __shared__ float Sl[4096];
    __shared__ float Wl[4096];
    __shared__ float cs[64];
    const int tid = threadIdx.x;
    const int k = blockIdx.x;
    for (int lin = tid; lin < 4096; lin += 64) {
        Sl[lin] = S[lin];
        Wl[lin] = W[k * 4096 + lin];   // Wl[i*64 + c]
    }
    cs[tid] = colsum[tid];
    __syncthreads();
    const int c = tid;
    float q = 0.f, sm = 0.f;
    for (int i = 0; i < 64; ++i) {
        float wi = Wl[i * 64 + c];
        sm += cs[i] * wi;
        float d = 0.f;
        #pragma unroll 8
        for (int j = 0; j < 64; ++j) d += Sl[i * 64 + j] * Wl[j * 64 + c];
        q += wi * d;
    }
    unsafeAtomicAdd(&stats[64 + c], q);
    unsafeAtomicAdd(&stats[c], sm);
}

// ---------------------------------------------------------------------------
// multi_conv: per-tap compacted lists. Computes contributions for multi pairs,
// atomic-accumulates into out, and subtracts their sumsq from stats q.
// ---------------------------------------------------------------------------
__global__ __launch_bounds__(256) void multi_conv(const float* __restrict__ feats,
                                                  const unsigned short* __restrict__ wfrag,
                                                  const int* __restrict__ oidx,
                                                  const int* __restrict__ slab,
                                                  const int* __restrict__ klen,
                                                  float* __restrict__ out,
                                                  float* __restrict__ stats,
                                                  int Npts) {
    __shared__ unsigned short As[64 * 64];
    __shared__ unsigned short Wk[4096];
    __shared__ int Pm[64];
    __shared__ int Os[64];
    __shared__ float red[16 * 16];

    const int tid = threadIdx.x;
    const int k = blockIdx.y;
    const int len = klen[k];
    if (len == 0) return;

    // Stage W_k once per block.
    {
        v8bf* d = reinterpret_cast<v8bf*>(Wk);
        const v8bf* s = reinterpret_cast<const v8bf*>(wfrag + k * 4096);
        for (int j = tid; j < 512; j += 256) d[j] = s[j];
    }

    const int w = tid >> 6, l = tid & 63, cl = l & 15, hi = l >> 4;
    const v8bf* Wv = reinterpret_cast<const v8bf*>(Wk);

    f32x4 qm[4];
    #pragma unroll
    for (int t = 0; t < 4; ++t) qm[t] = (f32x4){0.f, 0.f, 0.f, 0.f};

    for (int t0 = blockIdx.x * 64; t0 < len; t0 += gridDim.x * 64) {
        __syncthreads();
        if (tid < 64) {
            int id = (t0 + tid < len) ? slab[k * Npts + t0 + tid] : -1;
            Pm[tid] = id;
            Os[tid] = (id >= 0) ? oidx[id * KVOL + k] : -1;
        }
        __syncthreads();
        #pragma unroll
        for (int e = 0; e < 4; ++e) {
            int lin = e * 1024 + tid * 4;
            int row = lin >> 6, col = lin & 63;
            int id = Pm[row];
            float4 v = make_float4(0.f, 0.f, 0.f, 0.f);
            if (id >= 0)
                v = *reinterpret_cast<const float4*>(feats + (size_t)id * 64 + col);
            As[lin + 0] = f2bf(v.x); As[lin + 1] = f2bf(v.y);
            As[lin + 2] = f2bf(v.z); As[lin + 3] = f2bf(v.w);
        }
        __syncthreads();

        const v8bf a0 = *reinterpret_cast<const v8bf*>(&As[(16 * w + cl) * 64 + hi * 8]);
        const v8bf a1 = *reinterpret_cast<const v8bf*>(&As[(16 * w + cl) * 64 + 32 + hi * 8]);
        f32x4 acc[4];
        #pragma unroll
        for (int t = 0; t < 4; ++t) acc[t] = (f32x4){0.f, 0.f, 0.f, 0.f};
        #pragma unroll
        for (int t = 0; t < 4; ++t) {
            v8bf b0 = Wv[(t * 2 + 0) * 64 + l];
            v8bf b1 = Wv[(t * 2 + 1) * 64 + l];
            acc[t] = __builtin_amdgcn_mfma_f32_16x16x32_bf16(b0, a0, acc[t], 0, 0, 0);
            acc[t] = __builtin_amdgcn_mfma_f32_16x16x32_bf16(b1, a1, acc[t], 0, 0, 0);
        }
        int o = Os[16 * w + cl];
        if (o >= 0) {
            float* dst = out + (size_t)o * 64 + hi * 4;
            #pragma unroll
            for (int t = 0; t < 4; ++t) {
                #pragma unroll
                for (int j = 0; j < 4; ++j)
                    unsafeAtomicAdd(dst + t * 16 + j, acc[t][j]);
                qm[t] += acc[t] * acc[t];
            }
        }
    }

    // Reduce qm (channel = t*16 + hi*4 + j) and subtract from stats q.
    #pragma unroll
    for (int m = 1; m < 16; m <<= 1)
        #pragma unroll
        for (int t = 0; t < 4; ++t)
            #pragma unroll
            for (int j = 0; j < 4; ++j)
                qm[t][j] += __shfl_xor(qm[t][j], m, 16);
    __syncthreads();
    if (cl == 0) {
        #pragma unroll
        for (int t = 0; t < 4; ++t)
            #pragma unroll
            for (int j = 0; j < 4; ++j)
                red[(w * 4 + hi) * 16 + t * 4 + j] = qm[t][j];
    }
    __syncthreads();
    if (tid < 64) {
        int t = tid >> 4, h = (tid >> 2) & 3, j = tid & 3;
        float qq = 0.f;
        #pragma unroll
        for (int ww = 0; ww < 4; ++ww) qq += red[(ww * 4 + h) * 16 + t * 4 + j];
        unsafeAtomicAdd(&stats[64 + tid], -qq);
    }
}

// Sumsq of accumulated multi rows (added to stats q).
__global__ __launch_bounds__(256) void multi_stats(const float* __restrict__ out,
                                                   const int* __restrict__ cnt,
                                                   float* __restrict__ stats, int Nout) {
    const int tid = threadIdx.x;
    const int cg  = tid & 15;
    const int rs  = tid >> 4;
    f32x4 q = {0.f, 0.f, 0.f, 0.f};
    for (long r = (long)blockIdx.x * 16 + rs; r < Nout; r += (long)gridDim.x * 16) {
        if (cnt[r] > 1) {
            f32x4 v = *reinterpret_cast<const f32x4*>(out + (size_t)r * 64 + cg * 4);
            q += v * v;
        }
    }
    __shared__ f32x4 qd[256];
    qd[tid] = q;
    __syncthreads();
    #pragma unroll
    for (int st = 8; st >= 1; st >>= 1) {
        if (rs < st) qd[tid] += qd[tid + 16 * st];
        __syncthreads();
    }
    if (rs == 0) {
        #pragma unroll
        for (int c = 0; c < 4; ++c)
            unsafeAtomicAdd(&stats[64 + cg * 4 + c], qd[tid][c]);
    }
}

// ---------------------------------------------------------------------------
// conv_apply: the single full conv pass. BN+LeakyReLU in-register, dwordx4
// nontemporal stores for single rows; multi rows skipped (done elsewhere).
// ---------------------------------------------------------------------------
__global__ __launch_bounds__(256) void conv_apply(const float* __restrict__ feats,
                                                  const unsigned short* __restrict__ wfrag,
                                                  const int* __restrict__ oidx,
                                                  const int* __restrict__ cnt,
                                                  const float* __restrict__ stats,
                                                  const float* __restrict__ gamma,
                                                  const float* __restrict__ beta,
                                                  float* __restrict__ out,
                                                  int Npts, int Nout) {
    __shared__ unsigned short As[64 * 64];
    __shared__ int Is[64 * KVOL];
    __shared__ unsigned short Ws[KG * 4096];

    const int tid  = threadIdx.x;
    const int base = blockIdx.x * 64;
    const int M    = Npts * KVOL;

    #pragma unroll
    for (int e = 0; e < 4; ++e) {
        int lin = e * 1024 + tid * 4;
        int row = lin >> 6, col = lin & 63;
        float4 v = make_float4(0.f, 0.f, 0.f, 0.f);
        if (base + row < Npts)
            v = *reinterpret_cast<const float4*>(feats + (size_t)(base + row) * 64 + col);
        As[lin + 0] = f2bf(v.x); As[lin + 1] = f2bf(v.y);
        As[lin + 2] = f2bf(v.z); As[lin + 3] = f2bf(v.w);
    }
    for (int lin = tid; lin < 64 * KVOL; lin += 256) {
        int g = base * KVOL + lin;
        int iv = 0x80000000;
        if (g < M) {
            int o = oidx[g];
            iv = o | (cnt[o] > 1 ? 0x80000000 : 0);
        }
        Is[lin] = iv;
    }
    __syncthreads();

    const int w = tid >> 6, l = tid & 63, cl = l & 15, hi = l >> 4;
    const bool valid = (base + 16 * w + cl) < Npts;
    const v8bf a0 = *reinterpret_cast<const v8bf*>(&As[(16 * w + cl) * 64 + hi * 8]);
    const v8bf a1 = *reinterpret_cast<const v8bf*>(&As[(16 * w + cl) * 64 + 32 + hi * 8]);
    const v8bf* wfv = reinterpret_cast<const v8bf*>(wfrag);
    v8bf*       Wv  = reinterpret_cast<v8bf*>(Ws);
    const v8bf* Wl  = reinterpret_cast<const v8bf*>(Ws);

    const float inv = 1.0f / (float)Nout;
    f32x4 scale4[4], shift4[4];
    #pragma unroll
    for (int t = 0; t < 4; ++t) {
        int c0 = t * 16 + hi * 4;
        f32x4 m4 = *reinterpret_cast<const f32x4*>(stats + c0);
        f32x4 v4 = *reinterpret_cast<const f32x4*>(stats + 64 + c0);
        f32x4 g4 = *reinterpret_cast<const f32x4*>(gamma + c0);
        f32x4 b4 = *reinterpret_cast<const f32x4*>(beta + c0);
        #pragma unroll
        for (int j = 0; j < 4; ++j) {
            float m   = m4[j] * inv;
            float var = v4[j] * inv - m * m;
            float sc  = g4[j] * rsqrtf(var + 1e-5f);
            scale4[t][j] = sc;
            shift4[t][j] = b4[j] - sc * m;
        }
    }

    for (int k0 = 0; k0 < KVOL; k0 += KG) {
        const int kn = (KVOL - k0) < KG ? (KVOL - k0) : KG;
        __syncthreads();
        for (int j = tid; j < kn * 512; j += 256)
            Wv[j] = wfv[k0 * 512 + j];
        __syncthreads();

        for (int dk = 0; dk < kn; ++dk) {
            const int k = k0 + dk;
            f32x4 acc[4];
            #pragma unroll
            for (int t = 0; t < 4; ++t) acc[t] = (f32x4){0.f, 0.f, 0.f, 0.f};
            #pragma unroll
            for (int t = 0; t < 4; ++t) {
                v8bf b0 = Wl[((dk * 4 + t) * 2 + 0) * 64 + l];
                v8bf b1 = Wl[((dk * 4 + t) * 2 + 1) * 64 + l];
                acc[t] = __builtin_amdgcn_mfma_f32_16x16x32_bf16(b0, a0, acc[t], 0, 0, 0);
                acc[t] = __builtin_amdgcn_mfma_f32_16x16x32_bf16(b1, a1, acc[t], 0, 0, 0);
            }
            int iv = Is[(16 * w + cl) * KVOL + k];
            if (valid && iv >= 0) {
                float* dst = out + (size_t)iv * 64 + hi * 4;
                #pragma unroll
                for (int t = 0; t < 4; ++t) {
                    f32x4 y = acc[t] * scale4[t] + shift4[t];
                    #pragma unroll
                    for (int j = 0; j < 4; ++j) y[j] = y[j] > 0.f ? y[j] : 0.01f * y[j];
                    __builtin_nontemporal_store(y, reinterpret_cast<f32x4*>(dst + t * 16));
                }
            }
        }
    }
}

// BN+LeakyReLU in place for multi rows.
__global__ __launch_bounds__(256) void multi_apply(float* __restrict__ out,
                                                   const int* __restrict__ cnt,
                                                   const float* __restrict__ stats,
                                                   const float* __restrict__ gamma,
                                                   const float* __restrict__ beta,
                                                   int Nout) {
    const int tid = threadIdx.x;
    const int cg  = tid & 15;
    const int rs  = tid >> 4;
    const float inv = 1.0f / (float)Nout;
    f32x4 scale, shift;
    #pragma unroll
    for (int c = 0; c < 4; ++c) {
        float m   = stats[cg * 4 + c] * inv;
        float var = stats[64 + cg * 4 + c] * inv - m * m;
        float sc  = gamma[cg * 4 + c] * rsqrtf(var + 1e-5f);
        scale[c]  = sc;
        shift[c]  = beta[cg * 4 + c] - sc * m;
    }
    for (long r = (long)blockIdx.x * 16 + rs; r < Nout; r += (long)gridDim.x * 16) {
        if (cnt[r] > 1) {
            f32x4* p = reinterpret_cast<f32x4*>(out + (size_t)r * 64 + cg * 4);
            f32x4 v = *p;
            v = v * scale + shift;
            #pragma unroll
            for (int c = 0; c < 4; ++c) v[c] = v[c] > 0.f ? v[c] : 0.01f * v[c];
            *p = v;
        }
    }
}

// ---------------------------------------------------------------------------
// Fallback path (round-1 structure).
// ---------------------------------------------------------------------------
__global__ __launch_bounds__(256) void conv_scatter_fb(const float* __restrict__ feats,
                                                       const unsigned short* __restrict__ wfrag,
                                                       const int* __restrict__ oidx,
                                                       float* __restrict__ out,
                                                       int Npts) {
    __shared__ unsigned short As[64 * 64];
    __shared__ int Is[64 * KVOL];
    const int tid  = threadIdx.x;
    const int base = blockIdx.x * 64;
    #pragma unroll
    for (int e = 0; e < 4; ++e) {
        int lin = e * 1024 + tid * 4;
        int row = lin >> 6, col = lin & 63;
        float4 v = make_float4(0.f, 0.f, 0.f, 0.f);
        if (base + row < Npts)
            v = *reinterpret_cast<const float4*>(feats + (size_t)(base + row) * 64 + col);
        As[lin + 0] = f2bf(v.x); As[lin + 1] = f2bf(v.y);
        As[lin + 2] = f2bf(v.z); As[lin + 3] = f2bf(v.w);
    }
    for (int lin = tid; lin < 64 * KVOL; lin += 256) {
        int g = base * KVOL + lin;
        Is[lin] = (g < Npts * KVOL) ? oidx[g] : 0;
    }
    __syncthreads();
    const int w = tid >> 6, l = tid & 63, cl = l & 15, hi = l >> 4;
    const v8bf a0 = *reinterpret_cast<const v8bf*>(&As[(16 * w + cl) * 64 + hi * 8]);
    const v8bf a1 = *reinterpret_cast<const v8bf*>(&As[(16 * w + cl) * 64 + 32 + hi * 8]);
    const v8bf* wf = reinterpret_cast<const v8bf*>(wfrag);
    for (int k = 0; k < KVOL; ++k) {
        f32x4 acc[4];
        #pragma unroll
        for (int t = 0; t < 4; ++t) acc[t] = (f32x4){0.f, 0.f, 0.f, 0.f};
        #pragma unroll
        for (int t = 0; t < 4; ++t) {
            v8bf b0 = wf[((k * 4 + t) * 2 + 0) * 64 + l];
            v8bf b1 = wf[((k * 4 + t) * 2 + 1) * 64 + l];
            acc[t] = __builtin_amdgcn_mfma_f32_16x16x32_bf16(b0, a0, acc[t], 0, 0, 0);
            acc[t] = __builtin_amdgcn_mfma_f32_16x16x32_bf16(b1, a1, acc[t], 0, 0, 0);
        }
        if ((base + 16 * w + cl) < Npts) {
            int o = Is[(16 * w + cl) * KVOL + k];
            float* dst = out + (size_t)o * 64 + hi * 4;
            #pragma unroll
            for (int t = 0; t < 4; ++t)
                #pragma unroll
                for (int j = 0; j < 4; ++j)
                    unsafeAtomicAdd(dst + t * 16 + j, acc[t][j]);
        }
    }
}

__global__ __launch_bounds__(256) void bn_stats(const float* __restrict__ out,
                                                float* __restrict__ stats,
                                                int Nout) {
    const int tid = threadIdx.x;
    const int cg  = tid & 15;
    const int rs  = tid >> 4;
    f32x4 s = {0.f, 0.f, 0.f, 0.f}, q = {0.f, 0.f, 0.f, 0.f};
    for (long r = (long)blockIdx.x * 16 + rs; r < Nout; r += (long)gridDim.x * 16) {
        f32x4 v = *reinterpret_cast<const f32x4*>(out + (size_t)r * 64 + cg * 4);
        s += v;
        q += v * v;
    }
    __shared__ f32x4 sd[256];
    __shared__ f32x4 qd[256];
    sd[tid] = s; qd[tid] = q;
    __syncthreads();
    #pragma unroll
    for (int st = 8; st >= 1; st >>= 1) {
        if (rs < st) { sd[tid] += sd[tid + 16 * st]; qd[tid] += qd[tid + 16 * st]; }
        __syncthreads();
    }
    if (rs == 0) {
        #pragma unroll
        for (int c = 0; c < 4; ++c) {
            unsafeAtomicAdd(&stats[cg * 4 + c],      sd[tid][c]);
            unsafeAtomicAdd(&stats[64 + cg * 4 + c], qd[tid][c]);
        }
    }
}

__global__ __launch_bounds__(256) void bn_apply(float* __restrict__ out,
                                                const float* __restrict__ stats,
                                                const float* __restrict__ gamma,
                                                const float* __restrict__ beta,
                                                int Nout) {
    const int tid = threadIdx.x;
    const int cg  = tid & 15;
    const int rs  = tid >> 4;
    const float inv = 1.0f / (float)Nout;
    f32x4 scale, shift;
    #pragma unroll
    for (int c = 0; c < 4; ++c) {
        float m   = stats[cg * 4 + c] * inv;
        float var = stats[64 + cg * 4 + c] * inv - m * m;
        float sc  = gamma[cg * 4 + c] * rsqrtf(var + 1e-5f);
        scale[c]  = sc;
        shift[c]  = beta[cg * 4 + c] - sc * m;
    }
    for (long r = (long)blockIdx.x * 16 + rs; r < Nout; r += (long)gridDim.x * 16) {
        f32x4* p = reinterpret_cast<f32x4*>(out + (size_t)r * 64 + cg * 4);
        f32x4 v = *p;
        v = v * scale + shift;
        #pragma unroll
        for (int c = 0; c < 4; ++c) v[c] = v[c] > 0.f ? v[c] : 0.01f * v[c];
        *p = v;
    }
}

extern "C" void kernel_launch(void* const* d_in, const int* in_sizes, int n_in,
                              void* d_out, int out_size, void* d_ws, size_t ws_size,
                              hipStream_t stream) {
    const float* feats = (const float*)d_in[1];
    const float* W     = (const float*)d_in[2];
    const float* gamma = (const float*)d_in[3];
    const float* beta  = (const float*)d_in[4];
    const int*   oidx  = (const int*)d_in[5];
    float* out = (float*)d_out;

    const int Npts = in_sizes[1] / 64;   // 100000
    const int Nout = out_size / 64;      // ~2.51M
    const int M    = Npts * KVOL;

    // Workspace layout
    char* ws = (char*)d_ws;
    float* stats  = (float*)ws;                          // 128 f32 @ 0
    float* colsum = (float*)(ws + 512);                  // 64 f32
    float* S      = (float*)(ws + 4096);                 // 4096 f32 (16 KiB)
    unsigned short* wfrag = (unsigned short*)(ws + 32768);   // 216 KiB
    int* klen = (int*)(ws + 262144);                     // 27 ints
    int* slab = (int*)(ws + 266240);                     // 27*Npts ints
    size_t cnt_off = ((size_t)266240 + (size_t)27 * Npts * 4 + 4095) & ~(size_t)4095;
    int* cnt = (int*)(ws + cnt_off);                     // Nout ints
    const size_t ws_need = cnt_off + (size_t)Nout * 4;

    int cgrid = (Npts + 63) / 64;

    if (ws_size >= ws_need) {
        hipMemsetAsync(ws, 0, 32768, stream);            // stats + colsum + S
        hipMemsetAsync(klen, 0, 128, stream);
        hipMemsetAsync(cnt, 0, (size_t)Nout * sizeof(int), stream);
        hipLaunchKernelGGL(prep_kernel, dim3(432), dim3(256), 0, stream, W, wfrag);
        hipLaunchKernelGGL(count_kernel, dim3(2048), dim3(256), 0, stream, oidx, cnt, M);
        hipLaunchKernelGGL(feat_stats, dim3(256), dim3(256), 0, stream, feats, colsum, S, Npts);
        hipLaunchKernelGGL(qall_mean, dim3(KVOL), dim3(64), 0, stream, W, colsum, S, stats);
        hipLaunchKernelGGL(compact_kernel, dim3(2048), dim3(256), 0, stream, oidx, cnt, klen, slab, Npts);
        hipLaunchKernelGGL(zero_multi, dim3(2048), dim3(256), 0, stream, out, cnt, Nout);
        hipLaunchKernelGGL(multi_conv, dim3(MCB, KVOL), dim3(256), 0, stream,
                           feats, wfrag, oidx, slab, klen, out, stats, Npts);
        hipLaunchKernelGGL(multi_stats, dim3(2048), dim3(256), 0, stream, out, cnt, stats, Nout);
        hipLaunchKernelGGL(conv_apply, dim3(cgrid), dim3(256), 0, stream,
                           feats, wfrag, oidx, cnt, stats, gamma, beta, out, Npts, Nout);
        hipLaunchKernelGGL(multi_apply, dim3(2048), dim3(256), 0, stream,
                           out, cnt, stats, gamma, beta, Nout);
    } else {
        hipMemsetAsync(d_out, 0, (size_t)out_size * sizeof(float), stream);
        hipMemsetAsync(ws, 0, 512, stream);
        hipLaunchKernelGGL(prep_kernel, dim3(432), dim3(256), 0, stream, W, wfrag);
        hipLaunchKernelGGL(conv_scatter_fb, dim3(cgrid), dim3(256), 0, stream,
                           feats, wfrag, oidx, out, Npts);
        hipLaunchKernelGGL(bn_stats, dim3(2048), dim3(256), 0, stream, out, (float*)ws, Nout);
        hipLaunchKernelGGL(bn_apply, dim3(2048), dim3(256), 0, stream, out, (float*)ws, gamma, beta, Nout);
    }
}

// Round 8
// 599.706 us; speedup vs baseline: 1.1400x; 1.1400x over previous
//
#include <hip/hip_runtime.h>
#include <hip/hip_bf16.h>

typedef __bf16 v8bf __attribute__((ext_vector_type(8)));
typedef float  f32x4 __attribute__((ext_vector_type(4)));

#define KVOL 27
#define KG   4   // taps staged to LDS per group

__device__ __forceinline__ unsigned short f2bf(float f) {
    unsigned int u = __float_as_uint(f);
    u = u + 0x7FFFu + ((u >> 16) & 1u);   // round-to-nearest-even
    return (unsigned short)(u >> 16);
}

// ---------------------------------------------------------------------------
// Prep: W [27][64in][64out] fp32 -> bf16 fragments (same layout serves as
// either MFMA operand). lane l, elem i holds W[k][s*32+(l>>4)*8+i][t*16+(l&15)]
// at ushort index (((k*4+t)*2+s)*64 + l)*8 + i. Also zeroes stats[128].
// ---------------------------------------------------------------------------
__global__ __launch_bounds__(256) void prep_kernel(const float* __restrict__ W,
                                                   unsigned short* __restrict__ wfrag,
                                                   float* __restrict__ stats) {
    if (blockIdx.x == 0 && threadIdx.x < 128) stats[threadIdx.x] = 0.0f;
    int d = blockIdx.x * 256 + threadIdx.x;
    if (d < KVOL * 64 * 64) {
        int i    = d & 7;
        int lane = (d >> 3) & 63;
        int s    = (d >> 9) & 1;
        int t    = (d >> 10) & 3;
        int k    = d >> 12;
        int kin  = s * 32 + (lane >> 4) * 8 + i;
        int c    = t * 16 + (lane & 15);
        wfrag[d] = f2bf(W[k * 4096 + kin * 64 + c]);
    }
}

__global__ __launch_bounds__(256) void count_kernel(const int* __restrict__ oidx,
                                                    int* __restrict__ cnt, int M) {
    for (int e = blockIdx.x * 256 + threadIdx.x; e < M; e += gridDim.x * 256)
        atomicAdd(&cnt[oidx[e]], 1);
}

// Zero only multi-contributor rows (cnt >= 2). 4 threads per row.
__global__ __launch_bounds__(256) void zero_multi(float* __restrict__ out,
                                                  const int* __restrict__ cnt, int Nout) {
    const int sub = threadIdx.x & 3;
    const long step = (long)gridDim.x * 64;
    for (long r = (long)blockIdx.x * 64 + (threadIdx.x >> 2); r < Nout; r += step) {
        if (cnt[r] > 1) {
            f32x4 z = {0.f, 0.f, 0.f, 0.f};
            f32x4* p = reinterpret_cast<f32x4*>(out + r * 64) + sub;
            p[0] = z; p[4] = z; p[8] = z; p[12] = z;
        }
    }
}

// Stage bf16 A tile from fp32 feats.
__device__ __forceinline__ void stage_A(const float* __restrict__ feats,
                                        unsigned short* As, int base, int Npts) {
    const int tid = threadIdx.x;
    #pragma unroll
    for (int e = 0; e < 4; ++e) {
        int lin = e * 1024 + tid * 4;
        int row = lin >> 6, col = lin & 63;
        float4 v = make_float4(0.f, 0.f, 0.f, 0.f);
        if (base + row < Npts)
            v = *reinterpret_cast<const float4*>(feats + (size_t)(base + row) * 64 + col);
        As[lin + 0] = f2bf(v.x);
        As[lin + 1] = f2bf(v.y);
        As[lin + 2] = f2bf(v.z);
        As[lin + 3] = f2bf(v.w);
    }
}

// ---------------------------------------------------------------------------
// Pass 1: conv -> stats (+ atomic scatter for multi rows). Swapped-operand
// MFMA: lane (hi,cl) holds channels t*16+hi*4+{0..3} of point-row cl.
// W fragments LDS-staged in KG-tap groups (shared by all 4 waves).
// s accumulates ALL contributions (mean is linear); q only single rows.
// Packs idx|multi-flag to pIs for pass 2.
// ---------------------------------------------------------------------------
__global__ __launch_bounds__(256) void conv_stats(const float* __restrict__ feats,
                                                  const unsigned short* __restrict__ wfrag,
                                                  const int* __restrict__ oidx,
                                                  const int* __restrict__ cnt,
                                                  int* __restrict__ pIs,
                                                  float* __restrict__ out,
                                                  float* __restrict__ stats,
                                                  int Npts) {
    __shared__ unsigned short As[64 * 64];
    __shared__ int Is[64 * KVOL];
    __shared__ unsigned short Ws[KG * 4096];
    __shared__ float red[16 * 32];

    const int tid  = threadIdx.x;
    const int base = blockIdx.x * 64;
    const int M    = Npts * KVOL;

    stage_A(feats, As, base, Npts);
    for (int lin = tid; lin < 64 * KVOL; lin += 256) {
        int g = base * KVOL + lin;
        int iv = 0;
        if (g < M) {
            int o = oidx[g];
            iv = o | (cnt[o] > 1 ? 0x80000000 : 0);
            pIs[g] = iv;
        }
        Is[lin] = iv;
    }
    __syncthreads();

    const int w = tid >> 6, l = tid & 63, cl = l & 15, hi = l >> 4;
    const bool valid = (base + 16 * w + cl) < Npts;
    const v8bf a0 = *reinterpret_cast<const v8bf*>(&As[(16 * w + cl) * 64 + hi * 8]);
    const v8bf a1 = *reinterpret_cast<const v8bf*>(&As[(16 * w + cl) * 64 + 32 + hi * 8]);
    const v8bf* wfv = reinterpret_cast<const v8bf*>(wfrag);
    v8bf*       Wv  = reinterpret_cast<v8bf*>(Ws);
    const v8bf* Wl  = reinterpret_cast<const v8bf*>(Ws);

    f32x4 s4[4], q4[4];
    #pragma unroll
    for (int t = 0; t < 4; ++t) { s4[t] = (f32x4){0.f,0.f,0.f,0.f}; q4[t] = (f32x4){0.f,0.f,0.f,0.f}; }

    for (int k0 = 0; k0 < KVOL; k0 += KG) {
        const int kn = (KVOL - k0) < KG ? (KVOL - k0) : KG;
        __syncthreads();                        // prior group's reads done
        for (int j = tid; j < kn * 512; j += 256)
            Wv[j] = wfv[k0 * 512 + j];
        __syncthreads();

        for (int dk = 0; dk < kn; ++dk) {
            const int k = k0 + dk;
            f32x4 acc[4];
            #pragma unroll
            for (int t = 0; t < 4; ++t) acc[t] = (f32x4){0.f, 0.f, 0.f, 0.f};
            #pragma unroll
            for (int t = 0; t < 4; ++t) {
                v8bf b0 = Wl[((dk * 4 + t) * 2 + 0) * 64 + l];
                v8bf b1 = Wl[((dk * 4 + t) * 2 + 1) * 64 + l];
                acc[t] = __builtin_amdgcn_mfma_f32_16x16x32_bf16(b0, a0, acc[t], 0, 0, 0);
                acc[t] = __builtin_amdgcn_mfma_f32_16x16x32_bf16(b1, a1, acc[t], 0, 0, 0);
            }
            if (valid) {
                int iv = Is[(16 * w + cl) * KVOL + k];
                #pragma unroll
                for (int t = 0; t < 4; ++t) s4[t] += acc[t];
                if (iv >= 0) {
                    #pragma unroll
                    for (int t = 0; t < 4; ++t) q4[t] += acc[t] * acc[t];
                } else {
                    int o = iv & 0x7fffffff;
                    float* dst = out + (size_t)o * 64 + hi * 4;
                    #pragma unroll
                    for (int t = 0; t < 4; ++t)
                        #pragma unroll
                        for (int j = 0; j < 4; ++j)
                            unsafeAtomicAdd(dst + t * 16 + j, acc[t][j]);
                }
            }
        }
    }

    // Reduce across the 16 cl-lanes of each (wave, hi) group.
    #pragma unroll
    for (int m = 1; m < 16; m <<= 1) {
        #pragma unroll
        for (int t = 0; t < 4; ++t)
            #pragma unroll
            for (int j = 0; j < 4; ++j) {
                s4[t][j] += __shfl_xor(s4[t][j], m, 16);
                q4[t][j] += __shfl_xor(q4[t][j], m, 16);
            }
    }
    if (cl == 0) {
        int g = w * 4 + hi;
        #pragma unroll
        for (int t = 0; t < 4; ++t)
            #pragma unroll
            for (int j = 0; j < 4; ++j) {
                red[g * 32 + t * 4 + j]      = s4[t][j];
                red[g * 32 + 16 + t * 4 + j] = q4[t][j];
            }
    }
    __syncthreads();
    if (tid < 64) {   // channel c = tid = t*16 + h*4 + j
        int t = tid >> 4, h = (tid >> 2) & 3, j = tid & 3;
        float ss = 0.f, qq = 0.f;
        #pragma unroll
        for (int ww = 0; ww < 4; ++ww) {
            ss += red[(ww * 4 + h) * 32 + t * 4 + j];
            qq += red[(ww * 4 + h) * 32 + 16 + t * 4 + j];
        }
        unsafeAtomicAdd(&stats[tid],      ss);
        unsafeAtomicAdd(&stats[64 + tid], qq);
    }
}

// Sumsq of accumulated multi rows (sum already counted in pass 1).
__global__ __launch_bounds__(256) void multi_stats(const float* __restrict__ out,
                                                   const int* __restrict__ cnt,
                                                   float* __restrict__ stats, int Nout) {
    const int tid = threadIdx.x;
    const int cg  = tid & 15;
    const int rs  = tid >> 4;
    f32x4 q = {0.f, 0.f, 0.f, 0.f};
    for (long r = (long)blockIdx.x * 16 + rs; r < Nout; r += (long)gridDim.x * 16) {
        if (cnt[r] > 1) {
            f32x4 v = *reinterpret_cast<const f32x4*>(out + (size_t)r * 64 + cg * 4);
            q += v * v;
        }
    }
    __shared__ f32x4 qd[256];
    qd[tid] = q;
    __syncthreads();
    #pragma unroll
    for (int st = 8; st >= 1; st >>= 1) {
        if (rs < st) qd[tid] += qd[tid + 16 * st];
        __syncthreads();
    }
    if (rs == 0) {
        #pragma unroll
        for (int c = 0; c < 4; ++c)
            unsafeAtomicAdd(&stats[64 + cg * 4 + c], qd[tid][c]);
    }
}

// ---------------------------------------------------------------------------
// Pass 2: recompute conv (LDS-staged W), BN+LeakyReLU in-register, PLAIN
// (cached) dwordx4 stores for single rows — L2 write-combines full rows.
// ---------------------------------------------------------------------------
__global__ __launch_bounds__(256) void conv_apply(const float* __restrict__ feats,
                                                  const unsigned short* __restrict__ wfrag,
                                                  const int* __restrict__ pIs,
                                                  const float* __restrict__ stats,
                                                  const float* __restrict__ gamma,
                                                  const float* __restrict__ beta,
                                                  float* __restrict__ out,
                                                  int Npts, int Nout) {
    __shared__ unsigned short As[64 * 64];
    __shared__ int Is[64 * KVOL];
    __shared__ unsigned short Ws[KG * 4096];

    const int tid  = threadIdx.x;
    const int base = blockIdx.x * 64;
    const int M    = Npts * KVOL;

    stage_A(feats, As, base, Npts);
    for (int lin = tid; lin < 64 * KVOL; lin += 256) {
        int g = base * KVOL + lin;
        Is[lin] = (g < M) ? pIs[g] : 0x80000000;   // invalid -> treat as multi (skip)
    }
    __syncthreads();

    const int w = tid >> 6, l = tid & 63, cl = l & 15, hi = l >> 4;
    const bool valid = (base + 16 * w + cl) < Npts;
    const v8bf a0 = *reinterpret_cast<const v8bf*>(&As[(16 * w + cl) * 64 + hi * 8]);
    const v8bf a1 = *reinterpret_cast<const v8bf*>(&As[(16 * w + cl) * 64 + 32 + hi * 8]);
    const v8bf* wfv = reinterpret_cast<const v8bf*>(wfrag);
    v8bf*       Wv  = reinterpret_cast<v8bf*>(Ws);
    const v8bf* Wl  = reinterpret_cast<const v8bf*>(Ws);

    const float inv = 1.0f / (float)Nout;
    f32x4 scale4[4], shift4[4];
    #pragma unroll
    for (int t = 0; t < 4; ++t) {
        int c0 = t * 16 + hi * 4;
        f32x4 m4 = *reinterpret_cast<const f32x4*>(stats + c0);
        f32x4 v4 = *reinterpret_cast<const f32x4*>(stats + 64 + c0);
        f32x4 g4 = *reinterpret_cast<const f32x4*>(gamma + c0);
        f32x4 b4 = *reinterpret_cast<const f32x4*>(beta + c0);
        #pragma unroll
        for (int j = 0; j < 4; ++j) {
            float m   = m4[j] * inv;
            float var = v4[j] * inv - m * m;
            float sc  = g4[j] * rsqrtf(var + 1e-5f);
            scale4[t][j] = sc;
            shift4[t][j] = b4[j] - sc * m;
        }
    }

    for (int k0 = 0; k0 < KVOL; k0 += KG) {
        const int kn = (KVOL - k0) < KG ? (KVOL - k0) : KG;
        __syncthreads();
        for (int j = tid; j < kn * 512; j += 256)
            Wv[j] = wfv[k0 * 512 + j];
        __syncthreads();

        for (int dk = 0; dk < kn; ++dk) {
            const int k = k0 + dk;
            f32x4 acc[4];
            #pragma unroll
            for (int t = 0; t < 4; ++t) acc[t] = (f32x4){0.f, 0.f, 0.f, 0.f};
            #pragma unroll
            for (int t = 0; t < 4; ++t) {
                v8bf b0 = Wl[((dk * 4 + t) * 2 + 0) * 64 + l];
                v8bf b1 = Wl[((dk * 4 + t) * 2 + 1) * 64 + l];
                acc[t] = __builtin_amdgcn_mfma_f32_16x16x32_bf16(b0, a0, acc[t], 0, 0, 0);
                acc[t] = __builtin_amdgcn_mfma_f32_16x16x32_bf16(b1, a1, acc[t], 0, 0, 0);
            }
            int iv = Is[(16 * w + cl) * KVOL + k];
            if (valid && iv >= 0) {
                float* dst = out + (size_t)iv * 64 + hi * 4;
                #pragma unroll
                for (int t = 0; t < 4; ++t) {
                    f32x4 y = acc[t] * scale4[t] + shift4[t];
                    #pragma unroll
                    for (int j = 0; j < 4; ++j) y[j] = y[j] > 0.f ? y[j] : 0.01f * y[j];
                    *reinterpret_cast<f32x4*>(dst + t * 16) = y;   // plain cached store
                }
            }
        }
    }
}

// BN+LeakyReLU in place for multi rows.
__global__ __launch_bounds__(256) void multi_apply(float* __restrict__ out,
                                                   const int* __restrict__ cnt,
                                                   const float* __restrict__ stats,
                                                   const float* __restrict__ gamma,
                                                   const float* __restrict__ beta,
                                                   int Nout) {
    const int tid = threadIdx.x;
    const int cg  = tid & 15;
    const int rs  = tid >> 4;
    const float inv = 1.0f / (float)Nout;
    f32x4 scale, shift;
    #pragma unroll
    for (int c = 0; c < 4; ++c) {
        float m   = stats[cg * 4 + c] * inv;
        float var = stats[64 + cg * 4 + c] * inv - m * m;
        float sc  = gamma[cg * 4 + c] * rsqrtf(var + 1e-5f);
        scale[c]  = sc;
        shift[c]  = beta[cg * 4 + c] - sc * m;
    }
    for (long r = (long)blockIdx.x * 16 + rs; r < Nout; r += (long)gridDim.x * 16) {
        if (cnt[r] > 1) {
            f32x4* p = reinterpret_cast<f32x4*>(out + (size_t)r * 64 + cg * 4);
            f32x4 v = *p;
            v = v * scale + shift;
            #pragma unroll
            for (int c = 0; c < 4; ++c) v[c] = v[c] > 0.f ? v[c] : 0.01f * v[c];
            *p = v;
        }
    }
}

// ---------------------------------------------------------------------------
// Fallback path (round-1 structure).
// ---------------------------------------------------------------------------
__global__ __launch_bounds__(256) void conv_scatter_fb(const float* __restrict__ feats,
                                                       const unsigned short* __restrict__ wfrag,
                                                       const int* __restrict__ oidx,
                                                       float* __restrict__ out,
                                                       int Npts) {
    __shared__ unsigned short As[64 * 64];
    __shared__ int Is[64 * KVOL];
    const int tid  = threadIdx.x;
    const int base = blockIdx.x * 64;
    stage_A(feats, As, base, Npts);
    for (int lin = tid; lin < 64 * KVOL; lin += 256) {
        int g = base * KVOL + lin;
        Is[lin] = (g < Npts * KVOL) ? oidx[g] : 0;
    }
    __syncthreads();
    const int w = tid >> 6, l = tid & 63, cl = l & 15, hi = l >> 4;
    const v8bf a0 = *reinterpret_cast<const v8bf*>(&As[(16 * w + cl) * 64 + hi * 8]);
    const v8bf a1 = *reinterpret_cast<const v8bf*>(&As[(16 * w + cl) * 64 + 32 + hi * 8]);
    const v8bf* wf = reinterpret_cast<const v8bf*>(wfrag);
    for (int k = 0; k < KVOL; ++k) {
        f32x4 acc[4];
        #pragma unroll
        for (int t = 0; t < 4; ++t) acc[t] = (f32x4){0.f, 0.f, 0.f, 0.f};
        #pragma unroll
        for (int t = 0; t < 4; ++t) {
            v8bf b0 = wf[((k * 4 + t) * 2 + 0) * 64 + l];
            v8bf b1 = wf[((k * 4 + t) * 2 + 1) * 64 + l];
            acc[t] = __builtin_amdgcn_mfma_f32_16x16x32_bf16(b0, a0, acc[t], 0, 0, 0);
            acc[t] = __builtin_amdgcn_mfma_f32_16x16x32_bf16(b1, a1, acc[t], 0, 0, 0);
        }
        if ((base + 16 * w + cl) < Npts) {
            int o = Is[(16 * w + cl) * KVOL + k];
            float* dst = out + (size_t)o * 64 + hi * 4;
            #pragma unroll
            for (int t = 0; t < 4; ++t)
                #pragma unroll
                for (int j = 0; j < 4; ++j)
                    unsafeAtomicAdd(dst + t * 16 + j, acc[t][j]);
        }
    }
}

__global__ __launch_bounds__(256) void bn_stats(const float* __restrict__ out,
                                                float* __restrict__ stats,
                                                int Nout) {
    const int tid = threadIdx.x;
    const int cg  = tid & 15;
    const int rs  = tid >> 4;
    f32x4 s = {0.f, 0.f, 0.f, 0.f}, q = {0.f, 0.f, 0.f, 0.f};
    for (long r = (long)blockIdx.x * 16 + rs; r < Nout; r += (long)gridDim.x * 16) {
        f32x4 v = *reinterpret_cast<const f32x4*>(out + (size_t)r * 64 + cg * 4);
        s += v;
        q += v * v;
    }
    __shared__ f32x4 sd[256];
    __shared__ f32x4 qd[256];
    sd[tid] = s; qd[tid] = q;
    __syncthreads();
    #pragma unroll
    for (int st = 8; st >= 1; st >>= 1) {
        if (rs < st) { sd[tid] += sd[tid + 16 * st]; qd[tid] += qd[tid + 16 * st]; }
        __syncthreads();
    }
    if (rs == 0) {
        #pragma unroll
        for (int c = 0; c < 4; ++c) {
            unsafeAtomicAdd(&stats[cg * 4 + c],      sd[tid][c]);
            unsafeAtomicAdd(&stats[64 + cg * 4 + c], qd[tid][c]);
        }
    }
}

__global__ __launch_bounds__(256) void bn_apply(float* __restrict__ out,
                                                const float* __restrict__ stats,
                                                const float* __restrict__ gamma,
                                                const float* __restrict__ beta,
                                                int Nout) {
    const int tid = threadIdx.x;
    const int cg  = tid & 15;
    const int rs  = tid >> 4;
    const float inv = 1.0f / (float)Nout;
    f32x4 scale, shift;
    #pragma unroll
    for (int c = 0; c < 4; ++c) {
        float m   = stats[cg * 4 + c] * inv;
        float var = stats[64 + cg * 4 + c] * inv - m * m;
        float sc  = gamma[cg * 4 + c] * rsqrtf(var + 1e-5f);
        scale[c]  = sc;
        shift[c]  = beta[cg * 4 + c] - sc * m;
    }
    for (long r = (long)blockIdx.x * 16 + rs; r < Nout; r += (long)gridDim.x * 16) {
        f32x4* p = reinterpret_cast<f32x4*>(out + (size_t)r * 64 + cg * 4);
        f32x4 v = *p;
        v = v * scale + shift;
        #pragma unroll
        for (int c = 0; c < 4; ++c) v[c] = v[c] > 0.f ? v[c] : 0.01f * v[c];
        *p = v;
    }
}

extern "C" void kernel_launch(void* const* d_in, const int* in_sizes, int n_in,
                              void* d_out, int out_size, void* d_ws, size_t ws_size,
                              hipStream_t stream) {
    const float* feats = (const float*)d_in[1];
    const float* W     = (const float*)d_in[2];
    const float* gamma = (const float*)d_in[3];
    const float* beta  = (const float*)d_in[4];
    const int*   oidx  = (const int*)d_in[5];
    float* out = (float*)d_out;

    const int Npts = in_sizes[1] / 64;   // 100000
    const int Nout = out_size / 64;      // ~2.51M
    const int M    = Npts * KVOL;

    float*          stats = (float*)d_ws;                           // 128 floats @ 0
    unsigned short* wfrag = (unsigned short*)((char*)d_ws + 4096);  // 221184 B
    int*            cnt   = (int*)((char*)d_ws + (256 << 10));      // Nout ints
    int*            pIs   = (int*)((char*)d_ws + (16 << 20));       // M ints
    const size_t ws_need = (16 << 20) + (size_t)M * sizeof(int);

    int cgrid = (Npts + 63) / 64;

    if (ws_size >= ws_need && (size_t)(256 << 10) + (size_t)Nout * 4 <= (16 << 20)) {
        hipMemsetAsync(cnt, 0, (size_t)Nout * sizeof(int), stream);
        hipLaunchKernelGGL(prep_kernel, dim3(432), dim3(256), 0, stream, W, wfrag, stats);
        hipLaunchKernelGGL(count_kernel, dim3(2048), dim3(256), 0, stream, oidx, cnt, M);
        hipLaunchKernelGGL(zero_multi, dim3(2048), dim3(256), 0, stream, out, cnt, Nout);
        hipLaunchKernelGGL(conv_stats, dim3(cgrid), dim3(256), 0, stream,
                           feats, wfrag, oidx, cnt, pIs, out, stats, Npts);
        hipLaunchKernelGGL(multi_stats, dim3(2048), dim3(256), 0, stream, out, cnt, stats, Nout);
        hipLaunchKernelGGL(conv_apply, dim3(cgrid), dim3(256), 0, stream,
                           feats, wfrag, pIs, stats, gamma, beta, out, Npts, Nout);
        hipLaunchKernelGGL(multi_apply, dim3(2048), dim3(256), 0, stream,
                           out, cnt, stats, gamma, beta, Nout);
    } else {
        hipMemsetAsync(d_out, 0, (size_t)out_size * sizeof(float), stream);
        hipLaunchKernelGGL(prep_kernel, dim3(432), dim3(256), 0, stream, W, wfrag, stats);
        hipLaunchKernelGGL(conv_scatter_fb, dim3(cgrid), dim3(256), 0, stream,
                           feats, wfrag, oidx, out, Npts);
        hipLaunchKernelGGL(bn_stats, dim3(2048), dim3(256), 0, stream, out, stats, Nout);
        hipLaunchKernelGGL(bn_apply, dim3(2048), dim3(256), 0, stream, out, stats, gamma, beta, Nout);
    }
}